// Round 3
// baseline (142.590 us; speedup 1.0000x reference)
//
#include <hip/hip_runtime.h>
#include <hip/hip_bf16.h>

// GCN layer — R12: L2-resident gather via column-tiled Y planes.
// out = A·(X·W^T) + b   (R10/R11 algebraic reorder kept).
//   - Prepass GEMM (64 nodes/block) now writes Y as 4 column-planes:
//       plane p = Y[:, 32p..32p+31], contiguous 50000 x 64 B = 3.2 MB.
//   - Aggregation runs as 4 sequential pass-launches, one plane each.
//     Within a pass the gather working set is 3.2 MB < 4 MB per-XCD L2
//     (read-only -> replicated across XCDs), so gathers hit L2 (~34 TB/s)
//     instead of LLC. Total gather bytes unchanged (64 B/edge/pass x 4).
//   - Per-lane gather shrinks 16B->4B: xr[8] is 8 VGPR not 32, so the
//     8-deep batch fits at __launch_bounds__(256,7) without the R10 spill.
//   - Edge metadata re-staged per pass (+19 MB streaming, ~3 us) and
//     +3 launches — small vs the expected 25+ us gather win.

#define NPB     16    // nodes per main-kernel block
#define NPP     64    // nodes per prepass GEMM block (4 sub-tiles of 16)
#define BLOCK   256
#define D       128
#define CHUNK   512
#define ASTRIDE 136   // LDS row stride in shorts (128 + 8 pad)
#define PCOLS   32    // columns per Y plane

typedef __attribute__((ext_vector_type(8))) short bf16x8;
typedef __attribute__((ext_vector_type(4))) float f32x4;
typedef __attribute__((ext_vector_type(2))) float v2f;

__device__ __forceinline__ short f2bf(float f) {
    unsigned u = __float_as_uint(f);
    unsigned r = (u + 0x7fffu + ((u >> 16) & 1u)) >> 16;
    return (short)r;
}
__device__ __forceinline__ float bf_lo(int w) { return __int_as_float(w << 16); }
__device__ __forceinline__ float bf_hi(int w) { return __int_as_float(w & 0xffff0000); }

// ---------------- prepass: rs build + Y planes = bf16(X @ W^T) ----------------
__global__ __launch_bounds__(256, 4)
void prepass_kernel(const float* __restrict__ x,
                    const float* __restrict__ W,
                    const int*   __restrict__ edge_row,
                    short* __restrict__ yb,      // 4 planes, each n_nodes*PCOLS shorts
                    int*   __restrict__ rs,
                    int n_nodes, int n_edges, int gemm_blocks)
{
    const int bid = blockIdx.x;
    const int tid = threadIdx.x;

    if (bid >= gemm_blocks) {
        // ---- rs binary-search blocks ----
        const int gid = (bid - gemm_blocks) * 256 + tid;
        if (gid <= n_nodes) {
            int lo = 0, hi = n_edges;
            while (lo < hi) {
                int mid = (lo + hi) >> 1;
                bool lt = (edge_row[mid] < gid);
                lo = lt ? (mid + 1) : lo;
                hi = lt ? hi : mid;
            }
            rs[gid] = lo;
        }
        return;
    }

    // ---- GEMM block: 64-node tile of Y = bf16( x @ W^T ) ----
    __shared__ __align__(16) short xa_s[NPP * ASTRIDE];   // 17.0 KB bf16

    const int wave = tid >> 6;
    const int lane = tid & 63;
    const int tile_base = bid * NPP;

    // stage x tile -> bf16 LDS (64 rows x 128 feats); 2048 float4, coalesced
    #pragma unroll
    for (int t = 0; t < 8; ++t) {
        int idx = t * 256 + tid;        // 0..2047
        int row = idx >> 5;             // 32 float4 per row
        int c4  = idx & 31;
        int node = tile_base + row;
        float4 v = (node < n_nodes)
            ? reinterpret_cast<const float4*>(x)[(size_t)node * 32 + c4]
            : make_float4(0.f, 0.f, 0.f, 0.f);
        *reinterpret_cast<short4*>(&xa_s[row * ASTRIDE + c4 * 4]) =
            make_short4(f2bf(v.x), f2bf(v.y), f2bf(v.z), f2bf(v.w));
    }

    // B fragments from fp32 W, loaded once, reused by all 4 sub-tiles
    const int n16 = lane & 15;
    const int g   = lane >> 4;

    bf16x8 bfr[2][4];
    #pragma unroll
    for (int tt = 0; tt < 2; ++tt) {
        const int jt = 2 * wave + tt;
        const float* wrow = W + (size_t)(jt * 16 + n16) * D + g * 8;
        #pragma unroll
        for (int ks = 0; ks < 4; ++ks) {
            float4 wa  = *reinterpret_cast<const float4*>(wrow + ks * 32);
            float4 wb4 = *reinterpret_cast<const float4*>(wrow + ks * 32 + 4);
            bf16x8 f;
            f[0] = f2bf(wa.x);  f[1] = f2bf(wa.y);  f[2] = f2bf(wa.z);  f[3] = f2bf(wa.w);
            f[4] = f2bf(wb4.x); f[5] = f2bf(wb4.y); f[6] = f2bf(wb4.z); f[7] = f2bf(wb4.w);
            bfr[tt][ks] = f;
        }
    }

    __syncthreads();

    // 4 sub-tiles of 16 nodes; MFMA layout = verified R5-R8 phase-2
    #pragma unroll
    for (int st = 0; st < 4; ++st) {
        const int rbase = st * 16;
        bf16x8 afr[4];
        #pragma unroll
        for (int ks = 0; ks < 4; ++ks)
            afr[ks] = *reinterpret_cast<const bf16x8*>(
                &xa_s[(rbase + n16) * ASTRIDE + ks * 32 + g * 8]);

        #pragma unroll
        for (int tt = 0; tt < 2; ++tt) {
            const int jt = 2 * wave + tt;
            const int p  = jt >> 1;                    // Y plane (32 cols)
            const int c0 = (jt & 1) * 16 + n16;        // col within plane
            short* pl = yb + (size_t)p * n_nodes * PCOLS;
            f32x4 c = {0.f, 0.f, 0.f, 0.f};
            #pragma unroll
            for (int ks = 0; ks < 4; ++ks)
                c = __builtin_amdgcn_mfma_f32_16x16x32_bf16(afr[ks], bfr[tt][ks], c, 0, 0, 0);
            #pragma unroll
            for (int r = 0; r < 4; ++r) {
                int node = tile_base + rbase + g * 4 + r;
                if (node < n_nodes)
                    pl[(size_t)node * PCOLS + c0] = f2bf(c[r]);
            }
        }
    }
}

// ---------------- pass kernel: out[:,32p..32p+31] = b + A · plane_p ----------------
__global__ __launch_bounds__(BLOCK, 7)
void gcn_pass_kernel(const short* __restrict__ plane,   // n_nodes x PCOLS bf16
                     const int*   __restrict__ rs_g,
                     const int*   __restrict__ edge_col,
                     const float* __restrict__ edge_val,
                     const float* __restrict__ bvec,
                     float*       __restrict__ out,
                     int n_nodes, int n_edges, int pass)
{
    __shared__ int2 cv_s[CHUNK];          // 4 KB
    __shared__ int  rs_s[NPB + 1];

    const int tid  = threadIdx.x;
    const int wave = tid >> 6;
    const int lane = tid & 63;
    const int tile_base = blockIdx.x * NPB;

    // ---- row starts ----
    if (tid <= NPB) rs_s[tid] = rs_g[min(tile_base + tid, n_nodes)];
    __syncthreads();

    const int E0 = __builtin_amdgcn_readfirstlane(rs_s[0]);
    const int E1 = __builtin_amdgcn_readfirstlane(rs_s[NPB]);
    const int cnt = min(E1 - E0, CHUNK);

    // ---- stage the block's edge range (tile degree ~256, <512 w.h.p.) ----
    for (int i = tid; i < cnt; i += BLOCK)
        cv_s[i] = make_int2(edge_col[E0 + i], __float_as_int(edge_val[E0 + i]));
    __syncthreads();

    // ---- quarter-wave-per-node gather (4 B/lane from L2-resident plane) ----
    const int pq = lane >> 4;             // quarter-wave id -> node within wave
    const int q  = lane & 15;             // dword within 64-B plane row
    const int n  = wave * 4 + pq;         // node within tile
    const int e0 = rs_s[n], e1 = rs_s[n + 1];
    const int cap  = E0 + cnt;
    const int ecap = min(e1, cap);
    const short* yq = plane + q * 2;      // +4 B per lane

    v2f acc = (v2f){0.f, 0.f};

    for (int e = e0; e < ecap; e += 8) {
        int2 cv[8];
        int  xr[8];
        #pragma unroll
        for (int u = 0; u < 8; ++u) {
            int idx = e + u;
            int il  = (idx < ecap) ? (idx - E0) : (e0 - E0);
            cv[u] = cv_s[il];
        }
        #pragma unroll
        for (int u = 0; u < 8; ++u)
            xr[u] = *reinterpret_cast<const int*>(yq + ((size_t)cv[u].x << 5));
        #pragma unroll
        for (int u = 0; u < 8; ++u) {
            float vm = (e + u < ecap) ? __int_as_float(cv[u].y) : 0.f;
            acc += (v2f){vm, vm} * (v2f){bf_lo(xr[u]), bf_hi(xr[u])};
        }
    }
    // cold slow path: only if tile degree exceeded CHUNK
    for (int e = max(e0, cap); e < e1; ++e) {
        int   c = edge_col[e];
        float v = edge_val[e];
        int  xr = *reinterpret_cast<const int*>(yq + ((size_t)c << 5));
        acc += (v2f){v, v} * (v2f){bf_lo(xr), bf_hi(xr)};
    }

    // ---- bias + coalesced fp32 store: 128 B per node (this pass's 32 cols) ----
    const int node = tile_base + n;
    if (node < n_nodes) {
        const int cbase = pass * PCOLS + q * 2;
        float2 bb = *reinterpret_cast<const float2*>(bvec + cbase);
        float2 o  = make_float2(acc.x + bb.x, acc.y + bb.y);
        *reinterpret_cast<float2*>(out + (size_t)node * D + cbase) = o;
    }
}

// ---------------- fallback (R5 kernel, fp32 gathers, no ws) ----------------
__global__ __launch_bounds__(BLOCK, 5)
void gcn_fallback_kernel(const float* __restrict__ x,
                         const int*   __restrict__ edge_row,
                         const int*   __restrict__ edge_col,
                         const float* __restrict__ edge_val,
                         const float* __restrict__ W,
                         const float* __restrict__ bvec,
                         float*       __restrict__ out,
                         int n_nodes, int n_edges)
{
    __shared__ __align__(16) short agg_s[NPB * ASTRIDE];
    __shared__ int rs_s[NPB + 1];

    const int tid  = threadIdx.x;
    const int wave = tid >> 6;
    const int lane = tid & 63;
    const int tile_base = blockIdx.x * NPB;

    if (tid <= NPB) {
        int target = tile_base + tid;
        if (target > n_nodes) target = n_nodes;
        int lo = 0, hi = n_edges;
        while (lo < hi) {
            int mid = (lo + hi) >> 1;
            lo = (edge_row[mid] < target) ? (mid + 1) : lo;
            hi = (edge_row[mid] < target) ? hi : mid;
        }
        rs_s[tid] = lo;
    }
    __syncthreads();

    {
        const int h = lane >> 5;
        const int q = lane & 31;
        const float* xq = x + (q << 2);

        #pragma unroll
        for (int ni = 0; ni < NPB / 4; ++ni) {
            const int n = wave + 4 * ni;
            const int e0 = __builtin_amdgcn_readfirstlane(rs_s[n]);
            const int e1 = __builtin_amdgcn_readfirstlane(rs_s[n + 1]);
            float ax = 0.f, ay = 0.f, az = 0.f, aw = 0.f;
            for (int e = e0; e < e1; e += 16) {
                #pragma unroll
                for (int u = 0; u < 8; ++u) {
                    int idx  = e + 2 * u + h;
                    int idxc = (idx < e1) ? idx : (e1 - 1);
                    int   c  = edge_col[idxc];
                    float vr = edge_val[idxc];
                    float v  = (idx < e1) ? vr : 0.f;
                    float4 xr = *reinterpret_cast<const float4*>(xq + ((size_t)c << 7));
                    ax += v * xr.x; ay += v * xr.y; az += v * xr.z; aw += v * xr.w;
                }
            }
            ax += __shfl_xor(ax, 32, 64); ay += __shfl_xor(ay, 32, 64);
            az += __shfl_xor(az, 32, 64); aw += __shfl_xor(aw, 32, 64);
            if (h == 0) {
                *reinterpret_cast<short4*>(&agg_s[n * ASTRIDE + (q << 2)]) =
                    make_short4(f2bf(ax), f2bf(ay), f2bf(az), f2bf(aw));
            }
        }
    }

    const int n16 = lane & 15;
    const int g   = lane >> 4;
    bf16x8 bfr[2][4];
    #pragma unroll
    for (int tt = 0; tt < 2; ++tt) {
        const int jt = 2 * wave + tt;
        const float* rowp = W + ((size_t)(jt * 16 + n16)) * D + g * 8;
        #pragma unroll
        for (int ks = 0; ks < 4; ++ks) {
            float4 wa  = *reinterpret_cast<const float4*>(rowp + ks * 32);
            float4 wb4 = *reinterpret_cast<const float4*>(rowp + ks * 32 + 4);
            bf16x8 f;
            f[0] = f2bf(wa.x);  f[1] = f2bf(wa.y);  f[2] = f2bf(wa.z);  f[3] = f2bf(wa.w);
            f[4] = f2bf(wb4.x); f[5] = f2bf(wb4.y); f[6] = f2bf(wb4.z); f[7] = f2bf(wb4.w);
            bfr[tt][ks] = f;
        }
    }
    __syncthreads();
    {
        bf16x8 afr[4];
        #pragma unroll
        for (int ks = 0; ks < 4; ++ks)
            afr[ks] = *reinterpret_cast<const bf16x8*>(&agg_s[n16 * ASTRIDE + ks * 32 + g * 8]);
        #pragma unroll
        for (int tt = 0; tt < 2; ++tt) {
            const int jt = 2 * wave + tt;
            const int j  = jt * 16 + n16;
            const float bj = bvec[j];
            f32x4 c = {0.f, 0.f, 0.f, 0.f};
            #pragma unroll
            for (int ks = 0; ks < 4; ++ks)
                c = __builtin_amdgcn_mfma_f32_16x16x32_bf16(afr[ks], bfr[tt][ks], c, 0, 0, 0);
            #pragma unroll
            for (int r = 0; r < 4; ++r) {
                int node = tile_base + g * 4 + r;
                if (node < n_nodes)
                    out[(size_t)node * D + j] = c[r] + bj;
            }
        }
    }
}

extern "C" void kernel_launch(void* const* d_in, const int* in_sizes, int n_in,
                              void* d_out, int out_size, void* d_ws, size_t ws_size,
                              hipStream_t stream) {
    const float* x        = (const float*)d_in[0];
    const int*   edge_row = (const int*)  d_in[1];
    const int*   edge_col = (const int*)  d_in[2];
    const float* edge_val = (const float*)d_in[3];
    const float* W        = (const float*)d_in[4];
    const float* b        = (const float*)d_in[5];
    float* out = (float*)d_out;

    const int n_nodes = in_sizes[0] / D;
    const int n_edges = in_sizes[1];
    const int grid = (n_nodes + NPB - 1) / NPB;

    const size_t yb_bytes = (size_t)n_nodes * D * sizeof(short);
    const size_t rs_bytes = (size_t)(n_nodes + 1) * sizeof(int);
    if (ws_size >= yb_bytes + rs_bytes) {
        short* yb = (short*)d_ws;
        int*   rs = (int*)((char*)d_ws + yb_bytes);
        const int gemm_blocks   = (n_nodes + NPP - 1) / NPP;  // 64 nodes each
        const int search_blocks = (n_nodes + 1 + 255) / 256;
        prepass_kernel<<<gemm_blocks + search_blocks, 256, 0, stream>>>(
            x, W, edge_row, yb, rs, n_nodes, n_edges, gemm_blocks);
        for (int p = 0; p < 4; ++p) {
            const short* plane = yb + (size_t)p * n_nodes * PCOLS;
            gcn_pass_kernel<<<grid, BLOCK, 0, stream>>>(plane, rs, edge_col, edge_val,
                                                        b, out, n_nodes, n_edges, p);
        }
    } else {
        gcn_fallback_kernel<<<grid, BLOCK, 0, stream>>>(x, edge_row, edge_col, edge_val,
                                                        W, b, out, n_nodes, n_edges);
    }
}

// Round 4
// 126.956 us; speedup vs baseline: 1.1231x; 1.1231x over previous
//
#include <hip/hip_runtime.h>
#include <hip/hip_bf16.h>

// GCN layer — R13: R11 structure (verified 125 us) + non-temporal hints.
// out = A·(X·W^T) + b.  Cache-blocking measured-failed (R12 +17.6us);
// this round attacks L2 pollution instead:
//   - main: NT stores for out (25.6MB, never re-read), NT loads for the
//     edge_col/edge_val stream (read once) -> per-XCD L2 keeps more of the
//     12.8MB Y gather target resident (capacity bound ~31% hit).
//   - prepass: NT loads for x (read once); NT stores for yb so dirty Y
//     lines are pushed to LLC immediately (gathers come from all XCDs —
//     a dirty line stuck in one XCD's L2 costs an extra hop for others).
// Everything else byte-identical to R11: 64-node prepass GEMM tiles,
// quarter-wave-per-node 8-deep gather batches, (256,6) launch bounds.

#define NPB     16    // nodes per main-kernel block
#define NPP     64    // nodes per prepass GEMM block (4 sub-tiles of 16)
#define BLOCK   256
#define D       128
#define CHUNK   512
#define ASTRIDE 136   // LDS row stride in shorts (128 + 8 pad)

typedef __attribute__((ext_vector_type(8))) short bf16x8;
typedef __attribute__((ext_vector_type(4))) float f32x4;
typedef __attribute__((ext_vector_type(2))) float v2f;
typedef __attribute__((ext_vector_type(4))) short s16x4;

__device__ __forceinline__ short f2bf(float f) {
    unsigned u = __float_as_uint(f);
    unsigned r = (u + 0x7fffu + ((u >> 16) & 1u)) >> 16;
    return (short)r;
}
__device__ __forceinline__ float bf_lo(int w) { return __int_as_float(w << 16); }
__device__ __forceinline__ float bf_hi(int w) { return __int_as_float(w & 0xffff0000); }

// ---------------- prepass: rs build + Yb = bf16(X @ W^T) ----------------
__global__ __launch_bounds__(256, 4)
void prepass_kernel(const float* __restrict__ x,
                    const float* __restrict__ W,
                    const int*   __restrict__ edge_row,
                    short* __restrict__ yb,
                    int*   __restrict__ rs,
                    int n_nodes, int n_edges, int gemm_blocks)
{
    const int bid = blockIdx.x;
    const int tid = threadIdx.x;

    if (bid >= gemm_blocks) {
        // ---- rs binary-search blocks ----
        const int gid = (bid - gemm_blocks) * 256 + tid;
        if (gid <= n_nodes) {
            int lo = 0, hi = n_edges;
            while (lo < hi) {
                int mid = (lo + hi) >> 1;
                bool lt = (edge_row[mid] < gid);
                lo = lt ? (mid + 1) : lo;
                hi = lt ? hi : mid;
            }
            rs[gid] = lo;
        }
        return;
    }

    // ---- GEMM block: yb[64-node tile] = bf16( x @ W^T ) ----
    __shared__ __align__(16) short xa_s[NPP * ASTRIDE];   // 17.0 KB bf16

    const int wave = tid >> 6;
    const int lane = tid & 63;
    const int tile_base = bid * NPP;

    // stage x tile -> bf16 LDS; 2048 float4, coalesced, NT (read-once)
    #pragma unroll
    for (int t = 0; t < 8; ++t) {
        int idx = t * 256 + tid;        // 0..2047
        int row = idx >> 5;             // 32 float4 per row
        int c4  = idx & 31;
        int node = tile_base + row;
        f32x4 v = {0.f, 0.f, 0.f, 0.f};
        if (node < n_nodes)
            v = __builtin_nontemporal_load(
                    reinterpret_cast<const f32x4*>(x) + ((size_t)node * 32 + c4));
        *reinterpret_cast<short4*>(&xa_s[row * ASTRIDE + c4 * 4]) =
            make_short4(f2bf(v[0]), f2bf(v[1]), f2bf(v[2]), f2bf(v[3]));
    }

    // B fragments from fp32 W (tiny, cached), loaded once for all 4 sub-tiles
    const int n16 = lane & 15;
    const int g   = lane >> 4;

    bf16x8 bfr[2][4];
    #pragma unroll
    for (int tt = 0; tt < 2; ++tt) {
        const int jt = 2 * wave + tt;
        const float* wrow = W + (size_t)(jt * 16 + n16) * D + g * 8;
        #pragma unroll
        for (int ks = 0; ks < 4; ++ks) {
            float4 wa  = *reinterpret_cast<const float4*>(wrow + ks * 32);
            float4 wb4 = *reinterpret_cast<const float4*>(wrow + ks * 32 + 4);
            bf16x8 f;
            f[0] = f2bf(wa.x);  f[1] = f2bf(wa.y);  f[2] = f2bf(wa.z);  f[3] = f2bf(wa.w);
            f[4] = f2bf(wb4.x); f[5] = f2bf(wb4.y); f[6] = f2bf(wb4.z); f[7] = f2bf(wb4.w);
            bfr[tt][ks] = f;
        }
    }

    __syncthreads();

    // 4 sub-tiles of 16 nodes; MFMA layout = verified R5-R8 phase-2
    #pragma unroll
    for (int st = 0; st < 4; ++st) {
        const int rbase = st * 16;
        bf16x8 afr[4];
        #pragma unroll
        for (int ks = 0; ks < 4; ++ks)
            afr[ks] = *reinterpret_cast<const bf16x8*>(
                &xa_s[(rbase + n16) * ASTRIDE + ks * 32 + g * 8]);

        #pragma unroll
        for (int tt = 0; tt < 2; ++tt) {
            const int jt = 2 * wave + tt;
            const int j  = jt * 16 + n16;
            f32x4 c = {0.f, 0.f, 0.f, 0.f};
            #pragma unroll
            for (int ks = 0; ks < 4; ++ks)
                c = __builtin_amdgcn_mfma_f32_16x16x32_bf16(afr[ks], bfr[tt][ks], c, 0, 0, 0);
            #pragma unroll
            for (int r = 0; r < 4; ++r) {
                int node = tile_base + rbase + g * 4 + r;
                if (node < n_nodes) {
                    // NT store: push to LLC so cross-XCD gathers hit cleanly
                    __builtin_nontemporal_store(f2bf(c[r]),
                                                yb + (size_t)node * D + j);
                }
            }
        }
    }
}

// ---------------- main kernel: out[i] = b + sum_e val[e] * Yb[col[e]] ----------------
__global__ __launch_bounds__(BLOCK, 6)
void gcn_main_kernel(const short* __restrict__ yb,
                     const int*   __restrict__ rs_g,
                     const int*   __restrict__ edge_col,
                     const float* __restrict__ edge_val,
                     const float* __restrict__ bvec,
                     float*       __restrict__ out,
                     int n_nodes, int n_edges)
{
    __shared__ int2 cv_s[CHUNK];          // 4 KB
    __shared__ int  rs_s[NPB + 1];

    const int tid  = threadIdx.x;
    const int wave = tid >> 6;
    const int lane = tid & 63;
    const int tile_base = blockIdx.x * NPB;

    // ---- Phase 0: row starts (one coalesced read) ----
    if (tid <= NPB) rs_s[tid] = rs_g[min(tile_base + tid, n_nodes)];
    __syncthreads();

    const int E0 = __builtin_amdgcn_readfirstlane(rs_s[0]);
    const int E1 = __builtin_amdgcn_readfirstlane(rs_s[NPB]);
    const int cnt = min(E1 - E0, CHUNK);

    // ---- stage the block's edge range once; NT loads (stream, read-once) ----
    for (int i = tid; i < cnt; i += BLOCK) {
        int   c = __builtin_nontemporal_load(edge_col + E0 + i);
        float v = __builtin_nontemporal_load(edge_val + E0 + i);
        cv_s[i] = make_int2(c, __float_as_int(v));
    }
    __syncthreads();

    // ---- quarter-wave-per-node gather + fp32 accumulate, 8-deep batches ----
    const int p = lane >> 4;              // quarter-wave id -> node within wave
    const int q = lane & 15;              // feature oct (8 bf16 = 16 B)
    const int n = wave * 4 + p;           // node within tile
    const int e0 = rs_s[n], e1 = rs_s[n + 1];
    const int cap  = E0 + cnt;
    const int ecap = min(e1, cap);
    const short* yq = yb + q * 8;

    v2f acc2[4];
    #pragma unroll
    for (int i = 0; i < 4; ++i) acc2[i] = (v2f){0.f, 0.f};

    for (int e = e0; e < ecap; e += 8) {
        int2 cv[8];
        int4 xr[8];
        // stage 1: 8 LDS metadata reads (broadcast within quarter-wave)
        #pragma unroll
        for (int u = 0; u < 8; ++u) {
            int idx = e + u;
            int il  = (idx < ecap) ? (idx - E0) : (e0 - E0);
            cv[u] = cv_s[il];
        }
        // stage 2: 8 gathers in flight (regular loads — want L2 caching)
        #pragma unroll
        for (int u = 0; u < 8; ++u)
            xr[u] = *reinterpret_cast<const int4*>(yq + ((size_t)cv[u].x << 7));
        // stage 3: packed float2 FMA
        #pragma unroll
        for (int u = 0; u < 8; ++u) {
            float vm = (e + u < ecap) ? __int_as_float(cv[u].y) : 0.f;
            v2f v2 = (v2f){vm, vm};
            acc2[0] += v2 * (v2f){bf_lo(xr[u].x), bf_hi(xr[u].x)};
            acc2[1] += v2 * (v2f){bf_lo(xr[u].y), bf_hi(xr[u].y)};
            acc2[2] += v2 * (v2f){bf_lo(xr[u].z), bf_hi(xr[u].z)};
            acc2[3] += v2 * (v2f){bf_lo(xr[u].w), bf_hi(xr[u].w)};
        }
    }
    // cold slow path: only if tile degree exceeded CHUNK (never for this graph)
    for (int e = max(e0, cap); e < e1; ++e) {
        int   c = edge_col[e];
        float v = edge_val[e];
        int4 xr = *reinterpret_cast<const int4*>(yq + ((size_t)c << 7));
        v2f v2 = (v2f){v, v};
        acc2[0] += v2 * (v2f){bf_lo(xr.x), bf_hi(xr.x)};
        acc2[1] += v2 * (v2f){bf_lo(xr.y), bf_hi(xr.y)};
        acc2[2] += v2 * (v2f){bf_lo(xr.z), bf_hi(xr.z)};
        acc2[3] += v2 * (v2f){bf_lo(xr.w), bf_hi(xr.w)};
    }

    // ---- bias + NT coalesced fp32 store (out is never re-read) ----
    const int node = tile_base + n;
    if (node < n_nodes) {
        const float* bq = bvec + q * 8;
        float4 b0 = *reinterpret_cast<const float4*>(bq);
        float4 b1 = *reinterpret_cast<const float4*>(bq + 4);
        float* orow = out + (size_t)node * D + q * 8;
        f32x4 o0 = {acc2[0].x + b0.x, acc2[0].y + b0.y,
                    acc2[1].x + b0.z, acc2[1].y + b0.w};
        f32x4 o1 = {acc2[2].x + b1.x, acc2[2].y + b1.y,
                    acc2[3].x + b1.z, acc2[3].y + b1.w};
        __builtin_nontemporal_store(o0, reinterpret_cast<f32x4*>(orow));
        __builtin_nontemporal_store(o1, reinterpret_cast<f32x4*>(orow + 4));
    }
}

// ---------------- fallback (R5 kernel, fp32 gathers, no ws) ----------------
__global__ __launch_bounds__(BLOCK, 5)
void gcn_fallback_kernel(const float* __restrict__ x,
                         const int*   __restrict__ edge_row,
                         const int*   __restrict__ edge_col,
                         const float* __restrict__ edge_val,
                         const float* __restrict__ W,
                         const float* __restrict__ bvec,
                         float*       __restrict__ out,
                         int n_nodes, int n_edges)
{
    __shared__ __align__(16) short agg_s[NPB * ASTRIDE];
    __shared__ int rs_s[NPB + 1];

    const int tid  = threadIdx.x;
    const int wave = tid >> 6;
    const int lane = tid & 63;
    const int tile_base = blockIdx.x * NPB;

    if (tid <= NPB) {
        int target = tile_base + tid;
        if (target > n_nodes) target = n_nodes;
        int lo = 0, hi = n_edges;
        while (lo < hi) {
            int mid = (lo + hi) >> 1;
            lo = (edge_row[mid] < target) ? (mid + 1) : lo;
            hi = (edge_row[mid] < target) ? hi : mid;
        }
        rs_s[tid] = lo;
    }
    __syncthreads();

    {
        const int h = lane >> 5;
        const int q = lane & 31;
        const float* xq = x + (q << 2);

        #pragma unroll
        for (int ni = 0; ni < NPB / 4; ++ni) {
            const int n = wave + 4 * ni;
            const int e0 = __builtin_amdgcn_readfirstlane(rs_s[n]);
            const int e1 = __builtin_amdgcn_readfirstlane(rs_s[n + 1]);
            float ax = 0.f, ay = 0.f, az = 0.f, aw = 0.f;
            for (int e = e0; e < e1; e += 16) {
                #pragma unroll
                for (int u = 0; u < 8; ++u) {
                    int idx  = e + 2 * u + h;
                    int idxc = (idx < e1) ? idx : (e1 - 1);
                    int   c  = edge_col[idxc];
                    float vr = edge_val[idxc];
                    float v  = (idx < e1) ? vr : 0.f;
                    float4 xr = *reinterpret_cast<const float4*>(xq + ((size_t)c << 7));
                    ax += v * xr.x; ay += v * xr.y; az += v * xr.z; aw += v * xr.w;
                }
            }
            ax += __shfl_xor(ax, 32, 64); ay += __shfl_xor(ay, 32, 64);
            az += __shfl_xor(az, 32, 64); aw += __shfl_xor(aw, 32, 64);
            if (h == 0) {
                *reinterpret_cast<short4*>(&agg_s[n * ASTRIDE + (q << 2)]) =
                    make_short4(f2bf(ax), f2bf(ay), f2bf(az), f2bf(aw));
            }
        }
    }

    const int n16 = lane & 15;
    const int g   = lane >> 4;
    bf16x8 bfr[2][4];
    #pragma unroll
    for (int tt = 0; tt < 2; ++tt) {
        const int jt = 2 * wave + tt;
        const float* rowp = W + ((size_t)(jt * 16 + n16)) * D + g * 8;
        #pragma unroll
        for (int ks = 0; ks < 4; ++ks) {
            float4 wa  = *reinterpret_cast<const float4*>(rowp + ks * 32);
            float4 wb4 = *reinterpret_cast<const float4*>(rowp + ks * 32 + 4);
            bf16x8 f;
            f[0] = f2bf(wa.x);  f[1] = f2bf(wa.y);  f[2] = f2bf(wa.z);  f[3] = f2bf(wa.w);
            f[4] = f2bf(wb4.x); f[5] = f2bf(wb4.y); f[6] = f2bf(wb4.z); f[7] = f2bf(wb4.w);
            bfr[tt][ks] = f;
        }
    }
    __syncthreads();
    {
        bf16x8 afr[4];
        #pragma unroll
        for (int ks = 0; ks < 4; ++ks)
            afr[ks] = *reinterpret_cast<const bf16x8*>(&agg_s[n16 * ASTRIDE + ks * 32 + g * 8]);
        #pragma unroll
        for (int tt = 0; tt < 2; ++tt) {
            const int jt = 2 * wave + tt;
            const int j  = jt * 16 + n16;
            const float bj = bvec[j];
            f32x4 c = {0.f, 0.f, 0.f, 0.f};
            #pragma unroll
            for (int ks = 0; ks < 4; ++ks)
                c = __builtin_amdgcn_mfma_f32_16x16x32_bf16(afr[ks], bfr[tt][ks], c, 0, 0, 0);
            #pragma unroll
            for (int r = 0; r < 4; ++r) {
                int node = tile_base + g * 4 + r;
                if (node < n_nodes)
                    out[(size_t)node * D + j] = c[r] + bj;
            }
        }
    }
}

extern "C" void kernel_launch(void* const* d_in, const int* in_sizes, int n_in,
                              void* d_out, int out_size, void* d_ws, size_t ws_size,
                              hipStream_t stream) {
    const float* x        = (const float*)d_in[0];
    const int*   edge_row = (const int*)  d_in[1];
    const int*   edge_col = (const int*)  d_in[2];
    const float* edge_val = (const float*)d_in[3];
    const float* W        = (const float*)d_in[4];
    const float* b        = (const float*)d_in[5];
    float* out = (float*)d_out;

    const int n_nodes = in_sizes[0] / D;
    const int n_edges = in_sizes[1];
    const int grid = (n_nodes + NPB - 1) / NPB;

    const size_t yb_bytes = (size_t)n_nodes * D * sizeof(short);
    const size_t rs_bytes = (size_t)(n_nodes + 1) * sizeof(int);
    if (ws_size >= yb_bytes + rs_bytes) {
        short* yb = (short*)d_ws;
        int*   rs = (int*)((char*)d_ws + yb_bytes);
        const int gemm_blocks   = (n_nodes + NPP - 1) / NPP;  // 64 nodes each
        const int search_blocks = (n_nodes + 1 + 255) / 256;
        prepass_kernel<<<gemm_blocks + search_blocks, 256, 0, stream>>>(
            x, W, edge_row, yb, rs, n_nodes, n_edges, gemm_blocks);
        gcn_main_kernel<<<grid, BLOCK, 0, stream>>>(yb, rs, edge_col, edge_val,
                                                    b, out, n_nodes, n_edges);
    } else {
        gcn_fallback_kernel<<<grid, BLOCK, 0, stream>>>(x, edge_row, edge_col, edge_val,
                                                        W, b, out, n_nodes, n_edges);
    }
}